// Round 7
// baseline (1623.621 us; speedup 1.0000x reference)
//
#include <hip/hip_runtime.h>
#include <math.h>

#define DIM    8192
#define NHEADS 64
#define NKV    8
#define HD     128
#define BATCH  32
#define MAXSEQ 4096

// ---------------------------------------------------------------- zero
__global__ void zero_kernel(float* ws, float* out, int nws, int nout) {
  int total = nws + nout;
  for (int i = blockIdx.x * blockDim.x + threadIdx.x; i < total;
       i += gridDim.x * blockDim.x) {
    if (i < nws) ws[i] = 0.f;
    else out[i - nws] = 0.f;
  }
}

// ------------------------------------------------- fused QKV batched GEMV
// C[b][n] += sum_{k in chunk} X[b][k] * W[k][n]; one thread per column,
// 32 accumulators (one per batch row). K split across blockIdx.y.
template <int KC>
__global__ __launch_bounds__(256) void gemv_qkv_kernel(
    const float* __restrict__ x, const float* __restrict__ wq,
    const float* __restrict__ wk, const float* __restrict__ wv,
    float* qb, float* kb, float* vb) {
  const int nb = blockIdx.x;
  const int k0 = blockIdx.y * KC;

  const float* W;
  float* out;
  int N, col;
  if (nb < 32) {
    W = wq; out = qb; N = 8192; col = nb * 256 + threadIdx.x;
  } else if (nb < 36) {
    W = wk; out = kb; N = 1024; col = (nb - 32) * 256 + threadIdx.x;
  } else {
    W = wv; out = vb; N = 1024; col = (nb - 36) * 256 + threadIdx.x;
  }

  float acc[BATCH];
#pragma unroll
  for (int b = 0; b < BATCH; ++b) acc[b] = 0.f;

  const float* Wp = W + (size_t)k0 * N + col;
  const float* xp = x + k0;

  for (int kk = 0; kk < KC; kk += 4) {
    float w0 = Wp[0];
    float w1 = Wp[(size_t)N];
    float w2 = Wp[(size_t)2 * N];
    float w3 = Wp[(size_t)3 * N];
    Wp += (size_t)4 * N;
#pragma unroll
    for (int b = 0; b < BATCH; ++b) {
      const float* xb = xp + (size_t)b * DIM + kk;  // block-uniform -> s_load
      float a = acc[b];
      a = fmaf(xb[0], w0, a);
      a = fmaf(xb[1], w1, a);
      a = fmaf(xb[2], w2, a);
      a = fmaf(xb[3], w3, a);
      acc[b] = a;
    }
  }
#pragma unroll
  for (int b = 0; b < BATCH; ++b)
    atomicAdd(&out[(size_t)b * N + col], acc[b]);
}

// ---------------------------------------------------- output GEMV (wo)
template <int KC>
__global__ __launch_bounds__(256) void gemv_out_kernel(
    const float* __restrict__ X, const float* __restrict__ W,
    float* __restrict__ out) {
  const int N = 8192;
  const int col = blockIdx.x * 256 + threadIdx.x;
  const int k0 = blockIdx.y * KC;

  float acc[BATCH];
#pragma unroll
  for (int b = 0; b < BATCH; ++b) acc[b] = 0.f;

  const float* Wp = W + (size_t)k0 * N + col;
  const float* xp = X + k0;

  for (int kk = 0; kk < KC; kk += 4) {
    float w0 = Wp[0];
    float w1 = Wp[(size_t)N];
    float w2 = Wp[(size_t)2 * N];
    float w3 = Wp[(size_t)3 * N];
    Wp += (size_t)4 * N;
#pragma unroll
    for (int b = 0; b < BATCH; ++b) {
      const float* xb = xp + (size_t)b * DIM + kk;
      float a = acc[b];
      a = fmaf(xb[0], w0, a);
      a = fmaf(xb[1], w1, a);
      a = fmaf(xb[2], w2, a);
      a = fmaf(xb[3], w3, a);
      acc[b] = a;
    }
  }
#pragma unroll
  for (int b = 0; b < BATCH; ++b)
    atomicAdd(&out[(size_t)b * N + col], acc[b]);
}

// ---------------------------------------------------------------- RoPE
// rot_mat is 2x2-block-diagonal: out[2p] = a0*cos - a1*sin,
// out[2p+1] = a0*sin + a1*cos, with cos=rot[2p][2p], sin=rot[2p][2p+1].
__global__ void rope_kernel(float* qb, float* kb,
                            const float* __restrict__ rot) {
  const int total_q = BATCH * NHEADS * (HD / 2);
  const int total_k = BATCH * NKV * (HD / 2);
  int i = blockIdx.x * blockDim.x + threadIdx.x;
  float* base;
  int idx;
  if (i < total_q) {
    base = qb; idx = i;
  } else if (i < total_q + total_k) {
    base = kb; idx = i - total_q;
  } else {
    return;
  }
  const int p = idx & 63;    // pair index within head
  const int row = idx >> 6;  // (b*heads + h)
  const float c = rot[(size_t)(2 * p) * HD + 2 * p];
  const float s = rot[(size_t)(2 * p) * HD + 2 * p + 1];
  float* pr = base + (size_t)row * HD + 2 * p;
  const float a0 = pr[0], a1 = pr[1];
  pr[0] = a0 * c - a1 * s;
  pr[1] = a0 * s + a1 * c;
}

// ----------------------------------------------------------- attention
// One block per (b, kv-head g). 512 threads = 8 waves.
// Phase 1: thread-per-j K dot products (K read once, coalesced-by-row use).
// Phase 2: softmax (block max/sum via shuffle + LDS).
// Phase 3: waves stripe over j (V read ONCE per block), each wave
//          accumulates all 8 rep-head rows; cross-wave reduce via psum LDS.
__global__ __launch_bounds__(512) void attn_kernel(
    const float* __restrict__ qb, const float* __restrict__ kb,
    const float* __restrict__ vb, const float* __restrict__ cache_k,
    const float* __restrict__ cache_v, const int* __restrict__ spp,
    float* __restrict__ attn) {
  __shared__ float sc[8][2048];       // 64 KB scores/probs
  __shared__ float qs[8][HD];         // 4 KB
  __shared__ float psum[8][8][HD];    // 32 KB phase-3 partials [wave][row][d]
  __shared__ float redm[8][8];
  __shared__ float reds[8][8];

  const int bg = blockIdx.x;
  const int b = bg >> 3, g = bg & 7;
  const int tid = threadIdx.x;
  const int lane = tid & 63, wid = tid >> 6;
  const int sp = *spp;
  const int L = sp + 1;  // positions beyond sp are masked out exactly

  for (int i = tid; i < 8 * HD; i += 512) {
    int r = i >> 7, d = i & 127;
    qs[r][d] = qb[((size_t)b * NHEADS + g * 8 + r) * HD + d];
  }
  __syncthreads();

  const float scale = 0.08838834764831845f;  // 1/sqrt(128)
  const float* Kbase = cache_k + (size_t)bg * MAXSEQ * HD;
  const float* knew = kb + (size_t)bg * HD;

  float tmax[8];
#pragma unroll
  for (int r = 0; r < 8; ++r) tmax[r] = -1e30f;

  for (int j = tid; j < L; j += 512) {
    const float* kr = (j == sp) ? knew : (Kbase + (size_t)j * HD);
    float s[8];
#pragma unroll
    for (int r = 0; r < 8; ++r) s[r] = 0.f;
    for (int d = 0; d < HD; d += 4) {
      float4 kv = *(const float4*)(kr + d);
#pragma unroll
      for (int r = 0; r < 8; ++r) {
        float4 qv = *(const float4*)(&qs[r][d]);
        float a = s[r];
        a = fmaf(qv.x, kv.x, a);
        a = fmaf(qv.y, kv.y, a);
        a = fmaf(qv.z, kv.z, a);
        a = fmaf(qv.w, kv.w, a);
        s[r] = a;
      }
    }
#pragma unroll
    for (int r = 0; r < 8; ++r) {
      float v = s[r] * scale;
      sc[r][j] = v;
      tmax[r] = fmaxf(tmax[r], v);
    }
  }

#pragma unroll
  for (int r = 0; r < 8; ++r) {
    float v = tmax[r];
    for (int off = 32; off > 0; off >>= 1) v = fmaxf(v, __shfl_down(v, off));
    if (lane == 0) redm[r][wid] = v;
  }
  __syncthreads();

  float mrow[8];
#pragma unroll
  for (int r = 0; r < 8; ++r) {
    float m = redm[r][0];
#pragma unroll
    for (int w = 1; w < 8; ++w) m = fmaxf(m, redm[r][w]);
    mrow[r] = m;
  }

  float tsum[8];
#pragma unroll
  for (int r = 0; r < 8; ++r) tsum[r] = 0.f;
  for (int j = tid; j < L; j += 512) {
#pragma unroll
    for (int r = 0; r < 8; ++r) {
      float e = __expf(sc[r][j] - mrow[r]);
      sc[r][j] = e;
      tsum[r] += e;
    }
  }
#pragma unroll
  for (int r = 0; r < 8; ++r) {
    float v = tsum[r];
    for (int off = 32; off > 0; off >>= 1) v += __shfl_down(v, off);
    if (lane == 0) reds[r][wid] = v;
  }
  __syncthreads();

  // ---- phase 3: wave w handles j in {w, w+8, w+16, ...}; V read once.
  // Each lane accumulates 2 dims (dc, dc+1) for ALL 8 rep-head rows.
  const int dc = lane * 2;
  const float* Vbase = cache_v + (size_t)bg * MAXSEQ * HD;
  const float* vnew = vb + (size_t)bg * HD;

  float pa[8][2];
#pragma unroll
  for (int r = 0; r < 8; ++r) { pa[r][0] = 0.f; pa[r][1] = 0.f; }

#pragma unroll 4
  for (int j = wid; j < L; j += 8) {
    const float* vr = (j == sp) ? vnew : (Vbase + (size_t)j * HD);
    float2 vv = *(const float2*)(vr + dc);
#pragma unroll
    for (int r = 0; r < 8; ++r) {
      float p = sc[r][j];  // uniform across wave -> LDS broadcast
      pa[r][0] = fmaf(p, vv.x, pa[r][0]);
      pa[r][1] = fmaf(p, vv.y, pa[r][1]);
    }
  }

#pragma unroll
  for (int r = 0; r < 8; ++r) {
    psum[wid][r][dc] = pa[r][0];
    psum[wid][r][dc + 1] = pa[r][1];
  }
  __syncthreads();

  // wave r3 finalizes output row r3
  const int r3 = wid;
  float a0 = 0.f, a1 = 0.f;
#pragma unroll
  for (int w = 0; w < 8; ++w) {
    a0 += psum[w][r3][dc];
    a1 += psum[w][r3][dc + 1];
  }
  float dsum = 0.f;
#pragma unroll
  for (int w = 0; w < 8; ++w) dsum += reds[r3][w];
  const float dinv = 1.0f / dsum;
  float* op = attn + ((size_t)b * NHEADS + g * 8 + r3) * HD + dc;
  op[0] = a0 * dinv;
  op[1] = a1 * dinv;
}

// ---------------------------------------------------------------- launch
extern "C" void kernel_launch(void* const* d_in, const int* in_sizes, int n_in,
                              void* d_out, int out_size, void* d_ws,
                              size_t ws_size, hipStream_t stream) {
  const float* x   = (const float*)d_in[0];
  const float* wq  = (const float*)d_in[1];
  const float* wk  = (const float*)d_in[2];
  const float* wv  = (const float*)d_in[3];
  const float* wo  = (const float*)d_in[4];
  const float* rot = (const float*)d_in[5];
  const float* ck  = (const float*)d_in[6];
  const float* cv  = (const float*)d_in[7];
  const int*   sp  = (const int*)d_in[8];
  float* out = (float*)d_out;

  float* qb = (float*)d_ws;                      // 32*8192
  float* kb = qb + (size_t)BATCH * DIM;          // 32*1024
  float* vb = kb + (size_t)BATCH * NKV * HD;     // 32*1024
  float* attn = vb + (size_t)BATCH * NKV * HD;   // 32*8192

  const int nws = BATCH * DIM + 2 * BATCH * NKV * HD;  // q,k,v accumulators
  zero_kernel<<<1024, 256, 0, stream>>>(qb, out, nws, BATCH * DIM);

  gemv_qkv_kernel<512><<<dim3(40, 16), 256, 0, stream>>>(x, wq, wk, wv, qb,
                                                         kb, vb);

  const int pairs = BATCH * NHEADS * (HD / 2) + BATCH * NKV * (HD / 2);
  rope_kernel<<<(pairs + 255) / 256, 256, 0, stream>>>(qb, kb, rot);

  attn_kernel<<<BATCH * NKV, 512, 0, stream>>>(qb, kb, vb, ck, cv, sp, attn);

  gemv_out_kernel<512><<<dim3(32, 16), 256, 0, stream>>>(attn, wo, out);
}